// Round 7
// baseline (330.431 us; speedup 1.0000x reference)
//
#include <hip/hip_runtime.h>
#include <hip/hip_cooperative_groups.h>
#include <cstdint>
#include <cstddef>

// CNLinkPredictor on MI355X — round 7: single cooperative kernel, 3 phases.
//   phase 0: blocks 0..47 -> 6 weights to frag-major split-bf16 planes
//   phase 1: each block: fused_x tile (H = x + MLP(x)) ; then ballot-bitmask
//            grid-stride over adj (256 MB read = the structural HBM floor)
//   phase 2: each block: 32-edge chain: CN bit-scan + H-gather + xi*xj ->
//            XIJ -> T2 -> z(beta) -> L1 -> gemv, all in-LDS.
// grid.sync() between phases (hipLaunchCooperativeKernel; 256 blocks x 512
// thr = 1 block/CU by LDS). Layer math: split-bf16 (hi+lo, 3 MFMAs
// HH+HL+LH), mfma_f32_16x16x32_bf16, 8 waves, wave = 32 rows x 32 cols.

namespace cg = cooperative_groups;

#define C_DIM   256
#define N_NODES 8192
#define E_EDGES 8192

typedef short bf16x8 __attribute__((ext_vector_type(8)));
typedef float f32x4  __attribute__((ext_vector_type(4)));

struct Params {
    const float* x; const float* adj; const int* tar;
    const float* wm[6];     // xlin_w1, xlin_w2, xij_w, xcn_w1, xcn_w2, lin_w1
    const float* b1x; const float* b2x; const float* bxij;
    const float* bcn1; const float* bcn2; const float* blin1;
    const float* beta; const float* wv2; const float* b2o;
    unsigned long long* bits; short* WFH; short* WFL; float* Hbuf; float* out;
};

union SMem {
    struct { float tile[32][257]; } w;                                   // 33 KB
    struct { short PH[2][32][C_DIM]; short PL[2][32][C_DIM]; } fx;       // 64 KB
    struct {
        short PH[2][32][C_DIM]; short PL[2][32][C_DIM];                  // 64 KB
        float FO[32][C_DIM];                                             // 32 KB
        int eij[32][2]; int cncnt[32]; int cnlist[32][32]; float out32[32];
    } fe;                                                                // ~101 KB
};

__device__ __forceinline__ unsigned short bf16_rne(float a) {
    unsigned u = __float_as_uint(a);
    u += 0x7FFFu + ((u >> 16) & 1u);
    return (unsigned short)(u >> 16);
}
__device__ __forceinline__ void split2(float v, short& h, short& l) {
    unsigned short hb = bf16_rne(v);
    h = (short)hb;
    l = (short)bf16_rne(v - __uint_as_float((unsigned)hb << 16));
}

// ---- one split-bf16 layer: OUT = relu(IN @ W + b) [mode-variant] ----
// MODE 0: split -> POH/POL      MODE 1: v=v*beta+FO[r][c], split -> POH/POL
// MODE 2: FO[r][c]=v            MODE 3: Hg[m0+r][c] = v + xres[m0+r][c]
// MODE 4: gemv: out32[row] += sum_col v*w2[col]
template<int MODE>
__device__ __forceinline__ void layer_sb(
    const short (*INH)[C_DIM], const short (*INL)[C_DIM],
    const short* __restrict__ WH, const short* __restrict__ WL,
    const float* __restrict__ bias,
    short (*POH)[C_DIM], short (*POL)[C_DIM], float (*FO)[C_DIM],
    float* __restrict__ Hg, const float* __restrict__ xres, int m0,
    float beta, const float* __restrict__ w2, float* __restrict__ out32)
{
    const int t = threadIdx.x, lane = t & 63, wq = t >> 6;   // 8 waves
    const int fr = lane & 15, q = lane >> 4;
    f32x4 acc[2][2];
    #pragma unroll
    for (int i = 0; i < 2; ++i)
        #pragma unroll
        for (int j = 0; j < 2; ++j)
            #pragma unroll
            for (int r = 0; r < 4; ++r) acc[i][j][r] = 0.f;

    #pragma unroll 2
    for (int kf = 0; kf < 8; ++kf) {
        bf16x8 aH[2], aL[2];
        #pragma unroll
        for (int mf = 0; mf < 2; ++mf) {
            const int row = mf * 16 + fr;
            const int cc = (((kf << 2) + q) ^ (row & 7)) << 3;
            aH[mf] = *(const bf16x8*)&INH[row][cc];
            aL[mf] = *(const bf16x8*)&INL[row][cc];
        }
        #pragma unroll
        for (int nl = 0; nl < 2; ++nl) {
            const int nf = wq * 2 + nl;
            const int wo = (((kf << 4) + nf) * 64 + lane) * 8;
            bf16x8 bH = *(const bf16x8*)&WH[wo];
            bf16x8 bL = *(const bf16x8*)&WL[wo];
            #pragma unroll
            for (int mf = 0; mf < 2; ++mf) {
                acc[mf][nl] = __builtin_amdgcn_mfma_f32_16x16x32_bf16(aH[mf], bH, acc[mf][nl], 0, 0, 0);
                acc[mf][nl] = __builtin_amdgcn_mfma_f32_16x16x32_bf16(aH[mf], bL, acc[mf][nl], 0, 0, 0);
                acc[mf][nl] = __builtin_amdgcn_mfma_f32_16x16x32_bf16(aL[mf], bH, acc[mf][nl], 0, 0, 0);
            }
        }
    }

    float gs[2][4];
    if (MODE == 4) {
        #pragma unroll
        for (int mf = 0; mf < 2; ++mf)
            #pragma unroll
            for (int r = 0; r < 4; ++r) gs[mf][r] = 0.f;
    }
    #pragma unroll
    for (int nl = 0; nl < 2; ++nl) {
        const int col = wq * 32 + nl * 16 + fr;
        const float bb = bias[col];
        const float w2c = (MODE == 4) ? w2[col] : 0.f;
        #pragma unroll
        for (int mf = 0; mf < 2; ++mf)
            #pragma unroll
            for (int r = 0; r < 4; ++r) {
                const int row = mf * 16 + q * 4 + r;
                float v = fmaxf(acc[mf][nl][r] + bb, 0.f);
                if (MODE == 0 || MODE == 1) {
                    if (MODE == 1) v = v * beta + FO[row][col];
                    short h, l;
                    split2(v, h, l);
                    const int cw = (((col >> 3) ^ (row & 7)) << 3) + (col & 7);
                    POH[row][cw] = h;
                    POL[row][cw] = l;
                } else if (MODE == 2) {
                    FO[row][col] = v;
                } else if (MODE == 3) {
                    const size_t o = (size_t)(m0 + row) * C_DIM + col;
                    Hg[o] = v + xres[o];
                } else {
                    gs[mf][r] += v * w2c;
                }
            }
    }
    if (MODE == 4) {
        #pragma unroll
        for (int mf = 0; mf < 2; ++mf)
            #pragma unroll
            for (int r = 0; r < 4; ++r) {
                float s = gs[mf][r];
                s += __shfl_xor(s, 1); s += __shfl_xor(s, 2);
                s += __shfl_xor(s, 4); s += __shfl_xor(s, 8);
                if (fr == 0) atomicAdd(&out32[mf * 16 + q * 4 + r], s);
            }
    }
}

__global__ __launch_bounds__(512, 1) void k_mega(Params P) {
    __shared__ SMem sm;
    const int bid = blockIdx.x;
    const int t = threadIdx.x;
    cg::grid_group grid = cg::this_grid();

    // ================= phase 0: weights -> frag-major split planes =======
    if (bid < 48) {
        const int g = bid >> 3, kf = bid & 7;
        const float* W = P.wm[g];
        #pragma unroll
        for (int p = 0; p < 4; ++p) {
            int s = t + (p << 9);                // 2048 float4 slots
            int row = s >> 6, c4 = s & 63;
            float4 v = *(const float4*)&W[(size_t)(kf * 32 + row) * C_DIM + (c4 << 2)];
            sm.w.tile[row][(c4 << 2) + 0] = v.x; sm.w.tile[row][(c4 << 2) + 1] = v.y;
            sm.w.tile[row][(c4 << 2) + 2] = v.z; sm.w.tile[row][(c4 << 2) + 3] = v.w;
        }
        __syncthreads();
        #pragma unroll
        for (int p = 0; p < 2; ++p) {
            int s = t + (p << 9);                // 1024 (nf,lane) slots
            int nf = s >> 6, lane = s & 63;
            int q = lane >> 4, fr = lane & 15;
            short h[8], l[8];
            #pragma unroll
            for (int e = 0; e < 8; ++e)
                split2(sm.w.tile[q * 8 + e][nf * 16 + fr], h[e], l[e]);
            int dst = (g << 16) + (((kf * 16 + nf) << 6) + lane) * 8;
            *(short4*)&P.WFH[dst]     = make_short4(h[0], h[1], h[2], h[3]);
            *(short4*)&P.WFH[dst + 4] = make_short4(h[4], h[5], h[6], h[7]);
            *(short4*)&P.WFL[dst]     = make_short4(l[0], l[1], l[2], l[3]);
            *(short4*)&P.WFL[dst + 4] = make_short4(l[4], l[5], l[6], l[7]);
        }
    }
    __threadfence();
    grid.sync();

    // ================= phase 1a: fused_x tile ============================
    {
        const int m0 = bid << 5;
        #pragma unroll
        for (int p = 0; p < 4; ++p) {
            int s = t + (p << 9);
            int row = s >> 6, c4 = s & 63;
            float4 v = *(const float4*)&P.x[(size_t)(m0 + row) * C_DIM + (c4 << 2)];
            short h0, l0, h1, l1, h2, l2, h3, l3;
            split2(v.x, h0, l0); split2(v.y, h1, l1);
            split2(v.z, h2, l2); split2(v.w, h3, l3);
            int sw = (((c4 >> 1) ^ (row & 7)) << 3) + ((c4 & 1) << 2);
            *(short4*)&sm.fx.PH[0][row][sw] = make_short4(h0, h1, h2, h3);
            *(short4*)&sm.fx.PL[0][row][sw] = make_short4(l0, l1, l2, l3);
        }
        __syncthreads();
        layer_sb<0>(sm.fx.PH[0], sm.fx.PL[0], P.WFH + 0 * 65536, P.WFL + 0 * 65536,
                    P.b1x, sm.fx.PH[1], sm.fx.PL[1], nullptr, nullptr, nullptr, 0,
                    0.f, nullptr, nullptr);
        __syncthreads();
        layer_sb<3>(sm.fx.PH[1], sm.fx.PL[1], P.WFH + 1 * 65536, P.WFL + 1 * 65536,
                    P.b2x, nullptr, nullptr, nullptr, P.Hbuf, P.x, m0,
                    0.f, nullptr, nullptr);
    }

    // ================= phase 1b: bitmask (ballot, coalesced) =============
    {
        const int TOTALW = N_NODES * N_NODES / 64;        // 1M words
        const int gw   = (bid << 3) + (t >> 6);           // global wave 0..2047
        const int lane = t & 63;
        for (int w = gw << 3; w < TOTALW; w += 2048 * 8) {
            float v[8];
            #pragma unroll
            for (int r = 0; r < 8; ++r)
                v[r] = P.adj[((size_t)(w + r) << 6) + lane];
            #pragma unroll
            for (int r = 0; r < 8; ++r) {
                unsigned long long m = __ballot(v[r] > 0.5f);
                if (lane == 0) P.bits[w + r] = m;
            }
        }
    }
    __threadfence();
    grid.sync();

    // ================= phase 2: fused edge chain =========================
    {
        const int e0 = bid << 5;
        if (t < 32) {
            sm.fe.eij[t][0] = P.tar[e0 + t];
            sm.fe.eij[t][1] = P.tar[E_EDGES + e0 + t];
            sm.fe.cncnt[t] = 0;
            sm.fe.out32[t] = 0.f;
        }
        __syncthreads();
        // xij staging -> P0
        #pragma unroll
        for (int p = 0; p < 16; ++p) {
            int idx = (p << 9) + t;
            int e = idx >> 8, c = idx & 255;
            float v = P.x[(size_t)sm.fe.eij[e][0] * C_DIM + c] *
                      P.x[(size_t)sm.fe.eij[e][1] * C_DIM + c];
            short h, l;
            split2(v, h, l);
            int cw = (((c >> 3) ^ (e & 7)) << 3) + (c & 7);
            sm.fe.PH[0][e][cw] = h;
            sm.fe.PL[0][e][cw] = l;
        }
        // CN bit-scan: 16 threads/edge, 8 u64 words each
        {
            const int le = t >> 4, sub = t & 15;
            const size_t bi = (size_t)sm.fe.eij[le][0] * 128;
            const size_t bj = (size_t)sm.fe.eij[le][1] * 128;
            #pragma unroll
            for (int w8 = 0; w8 < 8; ++w8) {
                const int w = (sub << 3) + w8;
                unsigned long long m = P.bits[bi + w] & P.bits[bj + w];
                while (m) {
                    int b = __builtin_ctzll(m);
                    int slot = atomicAdd(&sm.fe.cncnt[le], 1);
                    if (slot < 32) sm.fe.cnlist[le][slot] = (w << 6) + b;
                    m &= m - 1;
                }
            }
        }
        __syncthreads();
        // CN gather -> P1
        #pragma unroll
        for (int p = 0; p < 16; ++p) {
            int idx = (p << 9) + t;
            int e = idx >> 8, c = idx & 255;
            float acc = 0.f;
            const int cnt = min(sm.fe.cncnt[e], 32);
            for (int q = 0; q < cnt; ++q)
                acc += P.Hbuf[(size_t)sm.fe.cnlist[e][q] * C_DIM + c];
            short h, l;
            split2(acc, h, l);
            int cw = (((c >> 3) ^ (e & 7)) << 3) + (c & 7);
            sm.fe.PH[1][e][cw] = h;
            sm.fe.PL[1][e][cw] = l;
        }
        __syncthreads();
        const float beta = P.beta[0];
        // XIJ = relu(xij @ xij_w + b) -> FO
        layer_sb<2>(sm.fe.PH[0], sm.fe.PL[0], P.WFH + 2 * 65536, P.WFL + 2 * 65536,
                    P.bxij, nullptr, nullptr, sm.fe.FO, nullptr, nullptr, 0,
                    0.f, nullptr, nullptr);
        __syncthreads();
        // T2 = relu(xcn @ xcn_w1 + b) -> P0
        layer_sb<0>(sm.fe.PH[1], sm.fe.PL[1], P.WFH + 3 * 65536, P.WFL + 3 * 65536,
                    P.bcn1, sm.fe.PH[0], sm.fe.PL[0], nullptr, nullptr, nullptr, 0,
                    0.f, nullptr, nullptr);
        __syncthreads();
        // z = relu(T2 @ xcn_w2 + b)*beta + XIJ -> P1
        layer_sb<1>(sm.fe.PH[0], sm.fe.PL[0], P.WFH + 4 * 65536, P.WFL + 4 * 65536,
                    P.bcn2, sm.fe.PH[1], sm.fe.PL[1], sm.fe.FO, nullptr, nullptr, 0,
                    beta, nullptr, nullptr);
        __syncthreads();
        // out = relu(z @ lin_w1 + b) @ w2  (gemv fused)
        layer_sb<4>(sm.fe.PH[1], sm.fe.PL[1], P.WFH + 5 * 65536, P.WFL + 5 * 65536,
                    P.blin1, nullptr, nullptr, nullptr, nullptr, nullptr, 0,
                    0.f, P.wv2, sm.fe.out32);
        __syncthreads();
        if (t < 32) P.out[e0 + t] = sm.fe.out32[t] + P.b2o[0];
    }
}

extern "C" void kernel_launch(void* const* d_in, const int* in_sizes, int n_in,
                              void* d_out, int out_size, void* d_ws, size_t ws_size,
                              hipStream_t stream) {
    const float* x       = (const float*)d_in[0];
    const float* adj     = (const float*)d_in[1];
    const int*   tar_ei  = (const int*)  d_in[2];
    const float* xlin_w1 = (const float*)d_in[3];
    const float* xlin_b1 = (const float*)d_in[4];
    const float* xlin_w2 = (const float*)d_in[5];
    const float* xlin_b2 = (const float*)d_in[6];
    const float* xcn_w1  = (const float*)d_in[7];
    const float* xcn_b1  = (const float*)d_in[8];
    const float* xcn_w2  = (const float*)d_in[9];
    const float* xcn_b2  = (const float*)d_in[10];
    const float* xij_w   = (const float*)d_in[11];
    const float* xij_b   = (const float*)d_in[12];
    const float* lin_w1  = (const float*)d_in[13];
    const float* lin_b1  = (const float*)d_in[14];
    const float* lin_w2  = (const float*)d_in[15];
    const float* lin_b2  = (const float*)d_in[16];
    const float* beta    = (const float*)d_in[17];

    char* ws = (char*)d_ws;
    const size_t MB = 1024 * 1024;

    Params P;
    P.x = x; P.adj = adj; P.tar = tar_ei;
    P.wm[0] = xlin_w1; P.wm[1] = xlin_w2; P.wm[2] = xij_w;
    P.wm[3] = xcn_w1;  P.wm[4] = xcn_w2;  P.wm[5] = lin_w1;
    P.b1x = xlin_b1; P.b2x = xlin_b2; P.bxij = xij_b;
    P.bcn1 = xcn_b1; P.bcn2 = xcn_b2; P.blin1 = lin_b1;
    P.beta = beta; P.wv2 = lin_w2; P.b2o = lin_b2;
    P.bits = (unsigned long long*)(ws);          // 8 MB
    P.WFH  = (short*)(ws +  8 * MB);             // 768 KB
    P.WFL  = (short*)(ws +  9 * MB);             // 768 KB
    P.Hbuf = (float*)(ws + 10 * MB);             // 8 MB
    P.out  = (float*)d_out;

    void* args[] = { &P };
    hipLaunchCooperativeKernel((const void*)k_mega, dim3(256), dim3(512),
                               args, 0, stream);
}

// Round 8
// 101.427 us; speedup vs baseline: 3.2578x; 3.2578x over previous
//
#include <hip/hip_runtime.h>
#include <cstdint>
#include <cstddef>

// CNLinkPredictor on MI355X — round 8: back to 3 kernels (coop grid.sync was
// a 300 us stall in round 7), with the bitmask rebuilt as coalesced ballot.
//   k_prep      : blocks 0..47    -> 6 weights to frag-major split planes
//                 blocks 48..2095 -> adj -> bitmask (ballot: lane=column,
//                 one 256B coalesced segment per load, 8 words/iter,
//                 nontemporal; 8 blocks/CU so HBM-bound not latency-bound)
//   k_fused_x   : x ->(LDS) relu(x@w1+b) -> H = x + relu(..@w2+b)  [32 rows/blk]
//   k_fused_edge: per 32-edge block: CN bit-scan + H-gather + xi*xj -> LDS;
//                 XIJ -> T2 -> z(beta) -> L1 -> gemv, all in-LDS.
//
// Layer math: split-bf16 (hi+lo, 3 MFMAs HH+HL+LH), mfma_f32_16x16x32_bf16,
// 8 waves, wave = 32 rows x 32 cols, K=256. Activations in LDS split planes
// [32][256], chunk-XOR swizzle (c8 ^= row&7) -> conflict-free ds_read_b128.
// Weights frag-major in global (L2-resident), one 16B load/lane/frag.

#define C_DIM   256
#define N_NODES 8192
#define E_EDGES 8192

typedef short bf16x8 __attribute__((ext_vector_type(8)));
typedef float f32x4  __attribute__((ext_vector_type(4)));

struct WPtrs { const float* p[6]; };

__device__ __forceinline__ unsigned short bf16_rne(float a) {
    unsigned u = __float_as_uint(a);
    u += 0x7FFFu + ((u >> 16) & 1u);
    return (unsigned short)(u >> 16);
}
__device__ __forceinline__ void split2(float v, short& h, short& l) {
    unsigned short hb = bf16_rne(v);
    h = (short)hb;
    l = (short)bf16_rne(v - __uint_as_float((unsigned)hb << 16));
}

// ---------------- prep: weights (blocks 0..47) + bitmask (blocks 48..) ------
__global__ __launch_bounds__(256) void k_prep(const float* __restrict__ adj,
                                              unsigned long long* __restrict__ bits,
                                              WPtrs wp, short* __restrict__ WFH,
                                              short* __restrict__ WFL) {
    const int t = threadIdx.x;
    if (blockIdx.x < 48) {
        __shared__ float tile[32][257];
        const int g  = blockIdx.x >> 3;
        const int kf = blockIdx.x & 7;
        const float* W = wp.p[g];
        #pragma unroll
        for (int p = 0; p < 8; ++p) {
            int s = t + (p << 8);
            int row = s >> 6, c4 = s & 63;
            float4 v = *(const float4*)&W[(size_t)(kf * 32 + row) * C_DIM + (c4 << 2)];
            tile[row][(c4 << 2) + 0] = v.x; tile[row][(c4 << 2) + 1] = v.y;
            tile[row][(c4 << 2) + 2] = v.z; tile[row][(c4 << 2) + 3] = v.w;
        }
        __syncthreads();
        #pragma unroll
        for (int p = 0; p < 4; ++p) {
            int s = t + (p << 8);
            int nf = s >> 6, lane = s & 63;
            int q = lane >> 4, fr = lane & 15;
            short h[8], l[8];
            #pragma unroll
            for (int e = 0; e < 8; ++e)
                split2(tile[q * 8 + e][nf * 16 + fr], h[e], l[e]);
            int dst = (g << 16) + (((kf * 16 + nf) << 6) + lane) * 8;
            *(short4*)&WFH[dst]     = make_short4(h[0], h[1], h[2], h[3]);
            *(short4*)&WFH[dst + 4] = make_short4(h[4], h[5], h[6], h[7]);
            *(short4*)&WFL[dst]     = make_short4(l[0], l[1], l[2], l[3]);
            *(short4*)&WFL[dst + 4] = make_short4(l[4], l[5], l[6], l[7]);
        }
    } else {
        // ---- bitmask: ballot, coalesced 256B per load, 8 words/iter ----
        const int TOTALW = N_NODES * N_NODES / 64;        // 1M words
        const int gw   = ((int)blockIdx.x - 48) * 4 + (t >> 6);   // 0..8191
        const int lane = t & 63;
        const int NW   = 2048 * 4;                         // 8192 waves
        for (int w = gw << 3; w < TOTALW; w += NW << 3) {
            float v[8];
            #pragma unroll
            for (int r = 0; r < 8; ++r)
                v[r] = __builtin_nontemporal_load(&adj[((size_t)(w + r) << 6) + lane]);
            unsigned long long m[8];
            #pragma unroll
            for (int r = 0; r < 8; ++r)
                m[r] = __ballot(v[r] > 0.5f);
            if (lane == 0) {
                #pragma unroll
                for (int r = 0; r < 4; ++r) {
                    ulonglong2 u2; u2.x = m[2 * r]; u2.y = m[2 * r + 1];
                    *(ulonglong2*)&bits[w + 2 * r] = u2;
                }
            }
        }
    }
}

// ---- one split-bf16 layer: OUT = relu(IN @ W + b) [mode-variant] ----
// MODE 0: split -> POH/POL      MODE 1: v=v*beta+FO[r][c], split -> POH/POL
// MODE 2: FO[r][c]=v            MODE 3: Hg[m0+r][c] = v + xres[m0+r][c]
// MODE 4: gemv: out32[row] += sum_col v*w2[col]
template<int MODE>
__device__ __forceinline__ void layer_sb(
    const short (*INH)[C_DIM], const short (*INL)[C_DIM],
    const short* __restrict__ WH, const short* __restrict__ WL,
    const float* __restrict__ bias,
    short (*POH)[C_DIM], short (*POL)[C_DIM], float (*FO)[C_DIM],
    float* __restrict__ Hg, const float* __restrict__ xres, int m0,
    float beta, const float* __restrict__ w2, float* __restrict__ out32)
{
    const int t = threadIdx.x, lane = t & 63, wq = t >> 6;   // 8 waves
    const int fr = lane & 15, q = lane >> 4;
    f32x4 acc[2][2];
    #pragma unroll
    for (int i = 0; i < 2; ++i)
        #pragma unroll
        for (int j = 0; j < 2; ++j)
            #pragma unroll
            for (int r = 0; r < 4; ++r) acc[i][j][r] = 0.f;

    #pragma unroll 2
    for (int kf = 0; kf < 8; ++kf) {
        bf16x8 aH[2], aL[2];
        #pragma unroll
        for (int mf = 0; mf < 2; ++mf) {
            const int row = mf * 16 + fr;
            const int cc = (((kf << 2) + q) ^ (row & 7)) << 3;
            aH[mf] = *(const bf16x8*)&INH[row][cc];
            aL[mf] = *(const bf16x8*)&INL[row][cc];
        }
        #pragma unroll
        for (int nl = 0; nl < 2; ++nl) {
            const int nf = wq * 2 + nl;
            const int wo = (((kf << 4) + nf) * 64 + lane) * 8;
            bf16x8 bH = *(const bf16x8*)&WH[wo];
            bf16x8 bL = *(const bf16x8*)&WL[wo];
            #pragma unroll
            for (int mf = 0; mf < 2; ++mf) {
                acc[mf][nl] = __builtin_amdgcn_mfma_f32_16x16x32_bf16(aH[mf], bH, acc[mf][nl], 0, 0, 0);
                acc[mf][nl] = __builtin_amdgcn_mfma_f32_16x16x32_bf16(aH[mf], bL, acc[mf][nl], 0, 0, 0);
                acc[mf][nl] = __builtin_amdgcn_mfma_f32_16x16x32_bf16(aL[mf], bH, acc[mf][nl], 0, 0, 0);
            }
        }
    }

    float gs[2][4];
    if (MODE == 4) {
        #pragma unroll
        for (int mf = 0; mf < 2; ++mf)
            #pragma unroll
            for (int r = 0; r < 4; ++r) gs[mf][r] = 0.f;
    }
    #pragma unroll
    for (int nl = 0; nl < 2; ++nl) {
        const int col = wq * 32 + nl * 16 + fr;
        const float bb = bias[col];
        const float w2c = (MODE == 4) ? w2[col] : 0.f;
        #pragma unroll
        for (int mf = 0; mf < 2; ++mf)
            #pragma unroll
            for (int r = 0; r < 4; ++r) {
                const int row = mf * 16 + q * 4 + r;
                float v = fmaxf(acc[mf][nl][r] + bb, 0.f);
                if (MODE == 0 || MODE == 1) {
                    if (MODE == 1) v = v * beta + FO[row][col];
                    short h, l;
                    split2(v, h, l);
                    const int cw = (((col >> 3) ^ (row & 7)) << 3) + (col & 7);
                    POH[row][cw] = h;
                    POL[row][cw] = l;
                } else if (MODE == 2) {
                    FO[row][col] = v;
                } else if (MODE == 3) {
                    const size_t o = (size_t)(m0 + row) * C_DIM + col;
                    Hg[o] = v + xres[o];
                } else {
                    gs[mf][r] += v * w2c;
                }
            }
    }
    if (MODE == 4) {
        #pragma unroll
        for (int mf = 0; mf < 2; ++mf)
            #pragma unroll
            for (int r = 0; r < 4; ++r) {
                float s = gs[mf][r];
                s += __shfl_xor(s, 1); s += __shfl_xor(s, 2);
                s += __shfl_xor(s, 4); s += __shfl_xor(s, 8);
                if (fr == 0) atomicAdd(&out32[mf * 16 + q * 4 + r], s);
            }
    }
}

// ---------------- fused x-chain: H = x + relu(relu(x@w1+b1)@w2+b2) ----------
__global__ __launch_bounds__(512, 1) void k_fused_x(
    const float* __restrict__ x, const short* __restrict__ WFH,
    const short* __restrict__ WFL, const float* __restrict__ b1,
    const float* __restrict__ b2, float* __restrict__ Hg)
{
    __shared__ short PH[2][32][C_DIM];
    __shared__ short PL[2][32][C_DIM];
    const int m0 = blockIdx.x << 5;
    const int t = threadIdx.x;
    #pragma unroll
    for (int p = 0; p < 4; ++p) {
        int s = t + (p << 9);
        int row = s >> 6, c4 = s & 63;
        float4 v = *(const float4*)&x[(size_t)(m0 + row) * C_DIM + (c4 << 2)];
        short h0, l0, h1, l1, h2, l2, h3, l3;
        split2(v.x, h0, l0); split2(v.y, h1, l1);
        split2(v.z, h2, l2); split2(v.w, h3, l3);
        int sw = (((c4 >> 1) ^ (row & 7)) << 3) + ((c4 & 1) << 2);
        *(short4*)&PH[0][row][sw] = make_short4(h0, h1, h2, h3);
        *(short4*)&PL[0][row][sw] = make_short4(l0, l1, l2, l3);
    }
    __syncthreads();
    layer_sb<0>(PH[0], PL[0], WFH + 0 * 65536, WFL + 0 * 65536, b1,
                PH[1], PL[1], nullptr, nullptr, nullptr, 0, 0.f, nullptr, nullptr);
    __syncthreads();
    layer_sb<3>(PH[1], PL[1], WFH + 1 * 65536, WFL + 1 * 65536, b2,
                nullptr, nullptr, nullptr, Hg, x, m0, 0.f, nullptr, nullptr);
}

// ---------------- fused edge-chain: scan + gather + 4 layers + gemv ---------
__global__ __launch_bounds__(512, 1) void k_fused_edge(
    const unsigned long long* __restrict__ bits, const float* __restrict__ x,
    const float* __restrict__ H, const int* __restrict__ tar,
    const short* __restrict__ WFH, const short* __restrict__ WFL,
    const float* __restrict__ bxij, const float* __restrict__ bcn1,
    const float* __restrict__ bcn2, const float* __restrict__ blin1,
    const float* __restrict__ betap, const float* __restrict__ w2,
    const float* __restrict__ b2, float* __restrict__ out)
{
    __shared__ short PH[2][32][C_DIM];
    __shared__ short PL[2][32][C_DIM];
    __shared__ float FO[32][C_DIM];
    __shared__ int   eij2[32][2];
    __shared__ int   cncnt[32];
    __shared__ int   cnlist[32][32];
    __shared__ float out32[32];
    const int e0 = blockIdx.x << 5;
    const int t = threadIdx.x;
    if (t < 32) {
        eij2[t][0] = tar[e0 + t];
        eij2[t][1] = tar[E_EDGES + e0 + t];
        cncnt[t] = 0;
        out32[t] = 0.f;
    }
    __syncthreads();
    // xij staging -> P0
    #pragma unroll
    for (int p = 0; p < 16; ++p) {
        int idx = (p << 9) + t;
        int e = idx >> 8, c = idx & 255;
        float v = x[(size_t)eij2[e][0] * C_DIM + c] * x[(size_t)eij2[e][1] * C_DIM + c];
        short h, l;
        split2(v, h, l);
        int cw = (((c >> 3) ^ (e & 7)) << 3) + (c & 7);
        PH[0][e][cw] = h;
        PL[0][e][cw] = l;
    }
    // CN bit-scan: 16 threads/edge, 8 u64 words each
    {
        const int le = t >> 4, sub = t & 15;
        const size_t bi = (size_t)eij2[le][0] * 128;
        const size_t bj = (size_t)eij2[le][1] * 128;
        #pragma unroll
        for (int w8 = 0; w8 < 8; ++w8) {
            const int w = (sub << 3) + w8;
            unsigned long long m = bits[bi + w] & bits[bj + w];
            while (m) {
                int b = __builtin_ctzll(m);
                int slot = atomicAdd(&cncnt[le], 1);
                if (slot < 32) cnlist[le][slot] = (w << 6) + b;
                m &= m - 1;
            }
        }
    }
    __syncthreads();
    // CN gather -> P1
    #pragma unroll
    for (int p = 0; p < 16; ++p) {
        int idx = (p << 9) + t;
        int e = idx >> 8, c = idx & 255;
        float acc = 0.f;
        const int cnt = min(cncnt[e], 32);
        for (int q = 0; q < cnt; ++q)
            acc += H[(size_t)cnlist[e][q] * C_DIM + c];
        short h, l;
        split2(acc, h, l);
        int cw = (((c >> 3) ^ (e & 7)) << 3) + (c & 7);
        PH[1][e][cw] = h;
        PL[1][e][cw] = l;
    }
    __syncthreads();
    const float beta = betap[0];
    // XIJ = relu(xij @ xij_w + b) -> FO
    layer_sb<2>(PH[0], PL[0], WFH + 2 * 65536, WFL + 2 * 65536, bxij,
                nullptr, nullptr, FO, nullptr, nullptr, 0, 0.f, nullptr, nullptr);
    __syncthreads();
    // T2 = relu(xcn @ xcn_w1 + b) -> P0
    layer_sb<0>(PH[1], PL[1], WFH + 3 * 65536, WFL + 3 * 65536, bcn1,
                PH[0], PL[0], nullptr, nullptr, nullptr, 0, 0.f, nullptr, nullptr);
    __syncthreads();
    // z = relu(T2 @ xcn_w2 + b)*beta + XIJ -> P1
    layer_sb<1>(PH[0], PL[0], WFH + 4 * 65536, WFL + 4 * 65536, bcn2,
                PH[1], PL[1], FO, nullptr, nullptr, 0, beta, nullptr, nullptr);
    __syncthreads();
    // out = relu(z @ lin_w1 + b) @ w2  (gemv fused)
    layer_sb<4>(PH[1], PL[1], WFH + 5 * 65536, WFL + 5 * 65536, blin1,
                nullptr, nullptr, nullptr, nullptr, nullptr, 0, 0.f, w2, out32);
    __syncthreads();
    if (t < 32) out[e0 + t] = out32[t] + b2[0];
}

extern "C" void kernel_launch(void* const* d_in, const int* in_sizes, int n_in,
                              void* d_out, int out_size, void* d_ws, size_t ws_size,
                              hipStream_t stream) {
    const float* x       = (const float*)d_in[0];
    const float* adj     = (const float*)d_in[1];
    const int*   tar_ei  = (const int*)  d_in[2];
    const float* xlin_w1 = (const float*)d_in[3];
    const float* xlin_b1 = (const float*)d_in[4];
    const float* xlin_w2 = (const float*)d_in[5];
    const float* xlin_b2 = (const float*)d_in[6];
    const float* xcn_w1  = (const float*)d_in[7];
    const float* xcn_b1  = (const float*)d_in[8];
    const float* xcn_w2  = (const float*)d_in[9];
    const float* xcn_b2  = (const float*)d_in[10];
    const float* xij_w   = (const float*)d_in[11];
    const float* xij_b   = (const float*)d_in[12];
    const float* lin_w1  = (const float*)d_in[13];
    const float* lin_b1  = (const float*)d_in[14];
    const float* lin_w2  = (const float*)d_in[15];
    const float* lin_b2  = (const float*)d_in[16];
    const float* beta    = (const float*)d_in[17];
    float* out = (float*)d_out;

    char* ws = (char*)d_ws;
    const size_t MB = 1024 * 1024;
    unsigned long long* bits = (unsigned long long*)(ws);       // 8 MB
    short* WFH  = (short*)(ws +  8 * MB);   // 768 KB
    short* WFL  = (short*)(ws +  9 * MB);   // 768 KB
    float* Hbuf = (float*)(ws + 10 * MB);   // 8 MB

    WPtrs wp;
    wp.p[0] = xlin_w1; wp.p[1] = xlin_w2; wp.p[2] = xij_w;
    wp.p[3] = xcn_w1;  wp.p[4] = xcn_w2;  wp.p[5] = lin_w1;

    hipLaunchKernelGGL(k_prep, dim3(48 + 2048), dim3(256), 0, stream,
                       adj, bits, wp, WFH, WFL);
    hipLaunchKernelGGL(k_fused_x, dim3(N_NODES / 32), dim3(512), 0, stream,
                       x, WFH, WFL, xlin_b1, xlin_b2, Hbuf);
    hipLaunchKernelGGL(k_fused_edge, dim3(E_EDGES / 32), dim3(512), 0, stream,
                       bits, x, Hbuf, tar_ei, WFH, WFL,
                       xij_b, xcn_b1, xcn_b2, lin_b1, beta, lin_w2, lin_b2, out);
}

// Round 9
// 91.461 us; speedup vs baseline: 3.6128x; 1.1090x over previous
//
#include <hip/hip_runtime.h>
#include <cstdint>
#include <cstddef>

// CNLinkPredictor on MI355X — round 9: 2 kernels (on-demand H).
//   k_prep     : blocks 0..47    -> 6 weights to frag-major split planes
//                blocks 48..2095 -> adj -> bitmask (ballot, coalesced)
//   k_edge_mega: per 32-edge block:
//                scan: bits[i]&bits[j] -> instance list (e,k)   [~4/block avg]
//                chunks of 32 instances: stage x[k] -> xlin layer1 -> layer2
//                  (+x resid) -> atomicAdd into XCN f32 LDS  [on-demand H]
//                XCN -> planes; xij -> planes; XIJ -> T2 -> z(beta) -> L1
//                -> gemv, all in-LDS.
//
// Rationale: full-graph H (8192 rows) was computed in its own kernel but only
// ~1024 CN rows are ever gathered. On-demand H kills a dispatch (~10us launch
// overhead) + 16MB Hbuf traffic. H math is bit-identical (same split-bf16
// planes, same weight frags, same MFMA order); only CN-sum order changes.
//
// Layer math: split-bf16 (hi+lo, 3 MFMAs HH+HL+LH), mfma_f32_16x16x32_bf16,
// 8 waves, wave = 32 rows x 32 cols, K=256. LDS planes [32][256] with
// chunk-XOR swizzle (c8 ^= row&7) -> conflict-free ds_read_b128. Weights
// frag-major in global (L2-resident), one 16B load/lane/frag.

#define C_DIM   256
#define N_NODES 8192
#define E_EDGES 8192

typedef short bf16x8 __attribute__((ext_vector_type(8)));
typedef float f32x4  __attribute__((ext_vector_type(4)));

struct WPtrs { const float* p[6]; };

__device__ __forceinline__ unsigned short bf16_rne(float a) {
    unsigned u = __float_as_uint(a);
    u += 0x7FFFu + ((u >> 16) & 1u);
    return (unsigned short)(u >> 16);
}
__device__ __forceinline__ void split2(float v, short& h, short& l) {
    unsigned short hb = bf16_rne(v);
    h = (short)hb;
    l = (short)bf16_rne(v - __uint_as_float((unsigned)hb << 16));
}

// ---------------- prep: weights (blocks 0..47) + bitmask (blocks 48..) ------
__global__ __launch_bounds__(256) void k_prep(const float* __restrict__ adj,
                                              unsigned long long* __restrict__ bits,
                                              WPtrs wp, short* __restrict__ WFH,
                                              short* __restrict__ WFL) {
    const int t = threadIdx.x;
    if (blockIdx.x < 48) {
        __shared__ float tile[32][257];
        const int g  = blockIdx.x >> 3;
        const int kf = blockIdx.x & 7;
        const float* W = wp.p[g];
        #pragma unroll
        for (int p = 0; p < 8; ++p) {
            int s = t + (p << 8);
            int row = s >> 6, c4 = s & 63;
            float4 v = *(const float4*)&W[(size_t)(kf * 32 + row) * C_DIM + (c4 << 2)];
            tile[row][(c4 << 2) + 0] = v.x; tile[row][(c4 << 2) + 1] = v.y;
            tile[row][(c4 << 2) + 2] = v.z; tile[row][(c4 << 2) + 3] = v.w;
        }
        __syncthreads();
        #pragma unroll
        for (int p = 0; p < 4; ++p) {
            int s = t + (p << 8);
            int nf = s >> 6, lane = s & 63;
            int q = lane >> 4, fr = lane & 15;
            short h[8], l[8];
            #pragma unroll
            for (int e = 0; e < 8; ++e)
                split2(tile[q * 8 + e][nf * 16 + fr], h[e], l[e]);
            int dst = (g << 16) + (((kf * 16 + nf) << 6) + lane) * 8;
            *(short4*)&WFH[dst]     = make_short4(h[0], h[1], h[2], h[3]);
            *(short4*)&WFH[dst + 4] = make_short4(h[4], h[5], h[6], h[7]);
            *(short4*)&WFL[dst]     = make_short4(l[0], l[1], l[2], l[3]);
            *(short4*)&WFL[dst + 4] = make_short4(l[4], l[5], l[6], l[7]);
        }
    } else {
        // ---- bitmask: ballot, one 256B coalesced segment per load ----
        const int TOTALW = N_NODES * N_NODES / 64;        // 1M words
        const int gw   = ((int)blockIdx.x - 48) * 4 + (t >> 6);   // 0..8191
        const int lane = t & 63;
        const int NW   = 2048 * 4;
        for (int w = gw << 3; w < TOTALW; w += NW << 3) {
            float v[8];
            #pragma unroll
            for (int r = 0; r < 8; ++r)
                v[r] = adj[((size_t)(w + r) << 6) + lane];
            unsigned long long m[8];
            #pragma unroll
            for (int r = 0; r < 8; ++r)
                m[r] = __ballot(v[r] > 0.5f);
            if (lane == 0) {
                #pragma unroll
                for (int r = 0; r < 4; ++r) {
                    ulonglong2 u2; u2.x = m[2 * r]; u2.y = m[2 * r + 1];
                    *(ulonglong2*)&bits[w + 2 * r] = u2;
                }
            }
        }
    }
}

// ---- split-bf16 layer core: OUT = relu(IN @ W + b), variants by MODE ----
// MODE 0: split -> POH/POL           MODE 1: v=v*beta+FO[r][c], split -> POH/POL
// MODE 2: FO[r][c]=v                 MODE 4: gemv: out32[row] += sum_col v*w2[col]
template<int MODE>
__device__ __forceinline__ void layer_sb(
    const short (*INH)[C_DIM], const short (*INL)[C_DIM],
    const short* __restrict__ WH, const short* __restrict__ WL,
    const float* __restrict__ bias,
    short (*POH)[C_DIM], short (*POL)[C_DIM], float (*FO)[C_DIM],
    float beta, const float* __restrict__ w2, float* __restrict__ out32)
{
    const int t = threadIdx.x, lane = t & 63, wq = t >> 6;   // 8 waves
    const int fr = lane & 15, q = lane >> 4;
    f32x4 acc[2][2];
    #pragma unroll
    for (int i = 0; i < 2; ++i)
        #pragma unroll
        for (int j = 0; j < 2; ++j)
            #pragma unroll
            for (int r = 0; r < 4; ++r) acc[i][j][r] = 0.f;

    #pragma unroll 2
    for (int kf = 0; kf < 8; ++kf) {
        bf16x8 aH[2], aL[2];
        #pragma unroll
        for (int mf = 0; mf < 2; ++mf) {
            const int row = mf * 16 + fr;
            const int cc = (((kf << 2) + q) ^ (row & 7)) << 3;
            aH[mf] = *(const bf16x8*)&INH[row][cc];
            aL[mf] = *(const bf16x8*)&INL[row][cc];
        }
        #pragma unroll
        for (int nl = 0; nl < 2; ++nl) {
            const int nf = wq * 2 + nl;
            const int wo = (((kf << 4) + nf) * 64 + lane) * 8;
            bf16x8 bH = *(const bf16x8*)&WH[wo];
            bf16x8 bL = *(const bf16x8*)&WL[wo];
            #pragma unroll
            for (int mf = 0; mf < 2; ++mf) {
                acc[mf][nl] = __builtin_amdgcn_mfma_f32_16x16x32_bf16(aH[mf], bH, acc[mf][nl], 0, 0, 0);
                acc[mf][nl] = __builtin_amdgcn_mfma_f32_16x16x32_bf16(aH[mf], bL, acc[mf][nl], 0, 0, 0);
                acc[mf][nl] = __builtin_amdgcn_mfma_f32_16x16x32_bf16(aL[mf], bH, acc[mf][nl], 0, 0, 0);
            }
        }
    }

    float gs[2][4];
    if (MODE == 4) {
        #pragma unroll
        for (int mf = 0; mf < 2; ++mf)
            #pragma unroll
            for (int r = 0; r < 4; ++r) gs[mf][r] = 0.f;
    }
    #pragma unroll
    for (int nl = 0; nl < 2; ++nl) {
        const int col = wq * 32 + nl * 16 + fr;
        const float bb = bias[col];
        const float w2c = (MODE == 4) ? w2[col] : 0.f;
        #pragma unroll
        for (int mf = 0; mf < 2; ++mf)
            #pragma unroll
            for (int r = 0; r < 4; ++r) {
                const int row = mf * 16 + q * 4 + r;
                float v = fmaxf(acc[mf][nl][r] + bb, 0.f);
                if (MODE == 0 || MODE == 1) {
                    if (MODE == 1) v = v * beta + FO[row][col];
                    short h, l;
                    split2(v, h, l);
                    const int cw = (((col >> 3) ^ (row & 7)) << 3) + (col & 7);
                    POH[row][cw] = h;
                    POL[row][cw] = l;
                } else if (MODE == 2) {
                    FO[row][col] = v;
                } else {
                    gs[mf][r] += v * w2c;
                }
            }
    }
    if (MODE == 4) {
        #pragma unroll
        for (int mf = 0; mf < 2; ++mf)
            #pragma unroll
            for (int r = 0; r < 4; ++r) {
                float s = gs[mf][r];
                s += __shfl_xor(s, 1); s += __shfl_xor(s, 2);
                s += __shfl_xor(s, 4); s += __shfl_xor(s, 8);
                if (fr == 0) atomicAdd(&out32[mf * 16 + q * 4 + r], s);
            }
    }
}

// ---- chunk layer-2: Hrow = relu(IN @ W + b) + x[k]; XCN[e] += Hrow ----
__device__ __forceinline__ void layer_h2(
    const short (*INH)[C_DIM], const short (*INL)[C_DIM],
    const short* __restrict__ WH, const short* __restrict__ WL,
    const float* __restrict__ bias, const int* __restrict__ inst, int nrows,
    const float* __restrict__ xsrc, float (*XCN)[C_DIM])
{
    const int t = threadIdx.x, lane = t & 63, wq = t >> 6;
    const int fr = lane & 15, q = lane >> 4;
    f32x4 acc[2][2];
    #pragma unroll
    for (int i = 0; i < 2; ++i)
        #pragma unroll
        for (int j = 0; j < 2; ++j)
            #pragma unroll
            for (int r = 0; r < 4; ++r) acc[i][j][r] = 0.f;

    #pragma unroll 2
    for (int kf = 0; kf < 8; ++kf) {
        bf16x8 aH[2], aL[2];
        #pragma unroll
        for (int mf = 0; mf < 2; ++mf) {
            const int row = mf * 16 + fr;
            const int cc = (((kf << 2) + q) ^ (row & 7)) << 3;
            aH[mf] = *(const bf16x8*)&INH[row][cc];
            aL[mf] = *(const bf16x8*)&INL[row][cc];
        }
        #pragma unroll
        for (int nl = 0; nl < 2; ++nl) {
            const int nf = wq * 2 + nl;
            const int wo = (((kf << 4) + nf) * 64 + lane) * 8;
            bf16x8 bH = *(const bf16x8*)&WH[wo];
            bf16x8 bL = *(const bf16x8*)&WL[wo];
            #pragma unroll
            for (int mf = 0; mf < 2; ++mf) {
                acc[mf][nl] = __builtin_amdgcn_mfma_f32_16x16x32_bf16(aH[mf], bH, acc[mf][nl], 0, 0, 0);
                acc[mf][nl] = __builtin_amdgcn_mfma_f32_16x16x32_bf16(aH[mf], bL, acc[mf][nl], 0, 0, 0);
                acc[mf][nl] = __builtin_amdgcn_mfma_f32_16x16x32_bf16(aL[mf], bH, acc[mf][nl], 0, 0, 0);
            }
        }
    }
    #pragma unroll
    for (int nl = 0; nl < 2; ++nl) {
        const int col = wq * 32 + nl * 16 + fr;
        const float bb = bias[col];
        #pragma unroll
        for (int mf = 0; mf < 2; ++mf)
            #pragma unroll
            for (int r = 0; r < 4; ++r) {
                const int row = mf * 16 + q * 4 + r;
                if (row < nrows) {
                    const int pk = inst[row];
                    const int e  = pk >> 16;
                    const int k  = pk & 0xffff;
                    float v = fmaxf(acc[mf][nl][r] + bb, 0.f) +
                              xsrc[(size_t)k * C_DIM + col];
                    atomicAdd(&XCN[e][col], v);
                }
            }
    }
}

// ---------------- edge mega-kernel ----------------
__global__ __launch_bounds__(512, 1) void k_edge_mega(
    const unsigned long long* __restrict__ bits, const float* __restrict__ x,
    const int* __restrict__ tar,
    const short* __restrict__ WFH, const short* __restrict__ WFL,
    const float* __restrict__ b1x, const float* __restrict__ b2x,
    const float* __restrict__ bxij, const float* __restrict__ bcn1,
    const float* __restrict__ bcn2, const float* __restrict__ blin1,
    const float* __restrict__ betap, const float* __restrict__ w2,
    const float* __restrict__ b2o, float* __restrict__ out)
{
    __shared__ short AH[32][C_DIM], AL[32][C_DIM];   // plane A (32 KB)
    __shared__ short BH[32][C_DIM], BL[32][C_DIM];   // plane B (32 KB)
    __shared__ float CF[32][C_DIM];                  // f32 buf: XCN accum -> FO (32 KB)
    __shared__ int   eij2[32][2];
    __shared__ int   inst[1024];
    __shared__ int   cntot;
    __shared__ float out32[32];
    const int e0 = blockIdx.x << 5;
    const int t = threadIdx.x;
    if (t < 32) {
        eij2[t][0] = tar[e0 + t];
        eij2[t][1] = tar[E_EDGES + e0 + t];
        out32[t] = 0.f;
    }
    if (t == 0) cntot = 0;
    __syncthreads();
    // zero XCN accumulator
    #pragma unroll
    for (int p = 0; p < 16; ++p) {
        int idx = (p << 9) + t;
        CF[idx >> 8][idx & 255] = 0.f;
    }
    // CN bit-scan: 16 threads/edge, 8 u64 words each -> instance list (e,k)
    {
        const int le = t >> 4, sub = t & 15;
        const size_t bi = (size_t)eij2[le][0] * 128;
        const size_t bj = (size_t)eij2[le][1] * 128;
        #pragma unroll
        for (int w8 = 0; w8 < 8; ++w8) {
            const int w = (sub << 3) + w8;
            unsigned long long m = bits[bi + w] & bits[bj + w];
            while (m) {
                int b = __builtin_ctzll(m);
                int slot = atomicAdd(&cntot, 1);
                if (slot < 1024) inst[slot] = (le << 16) | ((w << 6) + b);
                m &= m - 1;
            }
        }
    }
    __syncthreads();
    const int ctot = min(cntot, 1024);
    // ---- on-demand H: chunks of 32 CN instances ----
    for (int c0 = 0; c0 < ctot; c0 += 32) {
        const int nrows = min(32, ctot - c0);
        #pragma unroll
        for (int p = 0; p < 16; ++p) {
            int idx = (p << 9) + t;
            int r = idx >> 8, c = idx & 255;
            float v = 0.f;
            if (r < nrows) {
                int k = inst[c0 + r] & 0xffff;
                v = x[(size_t)k * C_DIM + c];
            }
            short h, l;
            split2(v, h, l);
            int cw = (((c >> 3) ^ (r & 7)) << 3) + (c & 7);
            AH[r][cw] = h;
            AL[r][cw] = l;
        }
        __syncthreads();
        layer_sb<0>(AH, AL, WFH + 0 * 65536, WFL + 0 * 65536, b1x,
                    BH, BL, nullptr, 0.f, nullptr, nullptr);
        __syncthreads();
        layer_h2(BH, BL, WFH + 1 * 65536, WFL + 1 * 65536, b2x,
                 inst + c0, nrows, x, CF);
        __syncthreads();
    }
    // ---- split XCN -> B planes ; stage xij -> A planes ----
    #pragma unroll
    for (int p = 0; p < 16; ++p) {
        int idx = (p << 9) + t;
        int r = idx >> 8, c = idx & 255;
        short h, l;
        split2(CF[r][c], h, l);
        int cw = (((c >> 3) ^ (r & 7)) << 3) + (c & 7);
        BH[r][cw] = h;
        BL[r][cw] = l;
    }
    __syncthreads();   // CF fully read before XIJ overwrites it
    #pragma unroll
    for (int p = 0; p < 16; ++p) {
        int idx = (p << 9) + t;
        int e = idx >> 8, c = idx & 255;
        float v = x[(size_t)eij2[e][0] * C_DIM + c] * x[(size_t)eij2[e][1] * C_DIM + c];
        short h, l;
        split2(v, h, l);
        int cw = (((c >> 3) ^ (e & 7)) << 3) + (c & 7);
        AH[e][cw] = h;
        AL[e][cw] = l;
    }
    __syncthreads();
    const float beta = betap[0];
    // XIJ = relu(xij @ xij_w + b) -> CF
    layer_sb<2>(AH, AL, WFH + 2 * 65536, WFL + 2 * 65536, bxij,
                nullptr, nullptr, CF, 0.f, nullptr, nullptr);
    __syncthreads();
    // T2 = relu(xcn @ xcn_w1 + b) -> A
    layer_sb<0>(BH, BL, WFH + 3 * 65536, WFL + 3 * 65536, bcn1,
                AH, AL, nullptr, 0.f, nullptr, nullptr);
    __syncthreads();
    // z = relu(T2 @ xcn_w2 + b)*beta + XIJ -> B
    layer_sb<1>(AH, AL, WFH + 4 * 65536, WFL + 4 * 65536, bcn2,
                BH, BL, CF, beta, nullptr, nullptr);
    __syncthreads();
    // out = relu(z @ lin_w1 + b) @ w2  (gemv fused)
    layer_sb<4>(BH, BL, WFH + 5 * 65536, WFL + 5 * 65536, blin1,
                nullptr, nullptr, nullptr, 0.f, w2, out32);
    __syncthreads();
    if (t < 32) out[e0 + t] = out32[t] + b2o[0];
}

extern "C" void kernel_launch(void* const* d_in, const int* in_sizes, int n_in,
                              void* d_out, int out_size, void* d_ws, size_t ws_size,
                              hipStream_t stream) {
    const float* x       = (const float*)d_in[0];
    const float* adj     = (const float*)d_in[1];
    const int*   tar_ei  = (const int*)  d_in[2];
    const float* xlin_w1 = (const float*)d_in[3];
    const float* xlin_b1 = (const float*)d_in[4];
    const float* xlin_w2 = (const float*)d_in[5];
    const float* xlin_b2 = (const float*)d_in[6];
    const float* xcn_w1  = (const float*)d_in[7];
    const float* xcn_b1  = (const float*)d_in[8];
    const float* xcn_w2  = (const float*)d_in[9];
    const float* xcn_b2  = (const float*)d_in[10];
    const float* xij_w   = (const float*)d_in[11];
    const float* xij_b   = (const float*)d_in[12];
    const float* lin_w1  = (const float*)d_in[13];
    const float* lin_b1  = (const float*)d_in[14];
    const float* lin_w2  = (const float*)d_in[15];
    const float* lin_b2  = (const float*)d_in[16];
    const float* beta    = (const float*)d_in[17];
    float* out = (float*)d_out;

    char* ws = (char*)d_ws;
    const size_t MB = 1024 * 1024;
    unsigned long long* bits = (unsigned long long*)(ws);       // 8 MB
    short* WFH  = (short*)(ws +  8 * MB);   // 768 KB
    short* WFL  = (short*)(ws +  9 * MB);   // 768 KB

    WPtrs wp;
    wp.p[0] = xlin_w1; wp.p[1] = xlin_w2; wp.p[2] = xij_w;
    wp.p[3] = xcn_w1;  wp.p[4] = xcn_w2;  wp.p[5] = lin_w1;

    hipLaunchKernelGGL(k_prep, dim3(48 + 2048), dim3(256), 0, stream,
                       adj, bits, wp, WFH, WFL);
    hipLaunchKernelGGL(k_edge_mega, dim3(E_EDGES / 32), dim3(512), 0, stream,
                       bits, x, tar_ei, WFH, WFL,
                       xlin_b1, xlin_b2, xij_b, xcn_b1, xcn_b2, lin_b1,
                       beta, lin_w2, lin_b2, out);
}

// Round 10
// 85.576 us; speedup vs baseline: 3.8612x; 1.0688x over previous
//
#include <hip/hip_runtime.h>
#include <cstdint>
#include <cstddef>

// CNLinkPredictor on MI355X — round 10: edge kernel at 1024 threads (16 waves,
// 4 waves/SIMD) to hide weight-load latency; wave = 32 rows x 16 cols.
//   k_prep     : blocks 0..47    -> 6 weights to frag-major split planes
//                blocks 48..2095 -> adj -> bitmask (ballot, coalesced)
//   k_edge_mega: per 32-edge block (1024 thr):
//                scan bits[i]&bits[j] -> instance list; on-demand H chunks
//                (xlin L1 -> L2 + x resid -> atomicAdd XCN in LDS f32);
//                XCN/xij -> planes; XIJ -> T2 -> z(beta) -> L1 -> gemv.
//
// Layer math: split-bf16 (hi+lo, 3 MFMAs HH+HL+LH), mfma_f32_16x16x32_bf16.
// 16 waves; wave wq owns nf=wq (16 cols), acc[2] m-frags, 48 MFMAs/layer.
// LDS planes [32][256] with chunk-XOR swizzle (c8 ^= row&7); weights
// frag-major in global (L2-resident), one 16B load/lane/frag.

#define C_DIM   256
#define N_NODES 8192
#define E_EDGES 8192

typedef short bf16x8 __attribute__((ext_vector_type(8)));
typedef float f32x4  __attribute__((ext_vector_type(4)));

struct WPtrs { const float* p[6]; };

__device__ __forceinline__ unsigned short bf16_rne(float a) {
    unsigned u = __float_as_uint(a);
    u += 0x7FFFu + ((u >> 16) & 1u);
    return (unsigned short)(u >> 16);
}
__device__ __forceinline__ void split2(float v, short& h, short& l) {
    unsigned short hb = bf16_rne(v);
    h = (short)hb;
    l = (short)bf16_rne(v - __uint_as_float((unsigned)hb << 16));
}

// ---------------- prep: weights (blocks 0..47) + bitmask (blocks 48..) ------
__global__ __launch_bounds__(256) void k_prep(const float* __restrict__ adj,
                                              unsigned long long* __restrict__ bits,
                                              WPtrs wp, short* __restrict__ WFH,
                                              short* __restrict__ WFL) {
    const int t = threadIdx.x;
    if (blockIdx.x < 48) {
        __shared__ float tile[32][257];
        const int g  = blockIdx.x >> 3;
        const int kf = blockIdx.x & 7;
        const float* W = wp.p[g];
        #pragma unroll
        for (int p = 0; p < 8; ++p) {
            int s = t + (p << 8);
            int row = s >> 6, c4 = s & 63;
            float4 v = *(const float4*)&W[(size_t)(kf * 32 + row) * C_DIM + (c4 << 2)];
            tile[row][(c4 << 2) + 0] = v.x; tile[row][(c4 << 2) + 1] = v.y;
            tile[row][(c4 << 2) + 2] = v.z; tile[row][(c4 << 2) + 3] = v.w;
        }
        __syncthreads();
        #pragma unroll
        for (int p = 0; p < 4; ++p) {
            int s = t + (p << 8);
            int nf = s >> 6, lane = s & 63;
            int q = lane >> 4, fr = lane & 15;
            short h[8], l[8];
            #pragma unroll
            for (int e = 0; e < 8; ++e)
                split2(tile[q * 8 + e][nf * 16 + fr], h[e], l[e]);
            int dst = (g << 16) + (((kf * 16 + nf) << 6) + lane) * 8;
            *(short4*)&WFH[dst]     = make_short4(h[0], h[1], h[2], h[3]);
            *(short4*)&WFH[dst + 4] = make_short4(h[4], h[5], h[6], h[7]);
            *(short4*)&WFL[dst]     = make_short4(l[0], l[1], l[2], l[3]);
            *(short4*)&WFL[dst + 4] = make_short4(l[4], l[5], l[6], l[7]);
        }
    } else {
        const int TOTALW = N_NODES * N_NODES / 64;        // 1M words
        const int gw   = ((int)blockIdx.x - 48) * 4 + (t >> 6);   // 0..8191
        const int lane = t & 63;
        const int NW   = 2048 * 4;
        for (int w = gw << 3; w < TOTALW; w += NW << 3) {
            float v[8];
            #pragma unroll
            for (int r = 0; r < 8; ++r)
                v[r] = adj[((size_t)(w + r) << 6) + lane];
            unsigned long long m[8];
            #pragma unroll
            for (int r = 0; r < 8; ++r)
                m[r] = __ballot(v[r] > 0.5f);
            if (lane == 0) {
                #pragma unroll
                for (int r = 0; r < 4; ++r) {
                    ulonglong2 u2; u2.x = m[2 * r]; u2.y = m[2 * r + 1];
                    *(ulonglong2*)&bits[w + 2 * r] = u2;
                }
            }
        }
    }
}

// ---- split-bf16 layer core, 16 waves: wave wq owns nf=wq (cols wq*16..+15) --
// MODE 0: split -> POH/POL           MODE 1: v=v*beta+FO[r][c], split -> POH/POL
// MODE 2: FO[r][c]=v                 MODE 4: gemv: out32[row] += sum_col v*w2[col]
template<int MODE>
__device__ __forceinline__ void layer_sb(
    const short (*INH)[C_DIM], const short (*INL)[C_DIM],
    const short* __restrict__ WH, const short* __restrict__ WL,
    const float* __restrict__ bias,
    short (*POH)[C_DIM], short (*POL)[C_DIM], float (*FO)[C_DIM],
    float beta, const float* __restrict__ w2, float* __restrict__ out32)
{
    const int t = threadIdx.x, lane = t & 63, wq = t >> 6;   // 16 waves
    const int fr = lane & 15, q = lane >> 4;
    f32x4 acc[2];
    #pragma unroll
    for (int i = 0; i < 2; ++i)
        #pragma unroll
        for (int r = 0; r < 4; ++r) acc[i][r] = 0.f;

    #pragma unroll 2
    for (int kf = 0; kf < 8; ++kf) {
        bf16x8 aH[2], aL[2];
        #pragma unroll
        for (int mf = 0; mf < 2; ++mf) {
            const int row = mf * 16 + fr;
            const int cc = (((kf << 2) + q) ^ (row & 7)) << 3;
            aH[mf] = *(const bf16x8*)&INH[row][cc];
            aL[mf] = *(const bf16x8*)&INL[row][cc];
        }
        const int wo = (((kf << 4) + wq) * 64 + lane) * 8;
        bf16x8 bH = *(const bf16x8*)&WH[wo];
        bf16x8 bL = *(const bf16x8*)&WL[wo];
        #pragma unroll
        for (int mf = 0; mf < 2; ++mf) {
            acc[mf] = __builtin_amdgcn_mfma_f32_16x16x32_bf16(aH[mf], bH, acc[mf], 0, 0, 0);
            acc[mf] = __builtin_amdgcn_mfma_f32_16x16x32_bf16(aH[mf], bL, acc[mf], 0, 0, 0);
            acc[mf] = __builtin_amdgcn_mfma_f32_16x16x32_bf16(aL[mf], bH, acc[mf], 0, 0, 0);
        }
    }

    const int col = (wq << 4) + fr;
    const float bb = bias[col];
    float gs[2][4];
    if (MODE == 4) {
        #pragma unroll
        for (int mf = 0; mf < 2; ++mf)
            #pragma unroll
            for (int r = 0; r < 4; ++r) gs[mf][r] = 0.f;
    }
    const float w2c = (MODE == 4) ? w2[col] : 0.f;
    #pragma unroll
    for (int mf = 0; mf < 2; ++mf)
        #pragma unroll
        for (int r = 0; r < 4; ++r) {
            const int row = mf * 16 + q * 4 + r;
            float v = fmaxf(acc[mf][r] + bb, 0.f);
            if (MODE == 0 || MODE == 1) {
                if (MODE == 1) v = v * beta + FO[row][col];
                short h, l;
                split2(v, h, l);
                const int cw = (((col >> 3) ^ (row & 7)) << 3) + (col & 7);
                POH[row][cw] = h;
                POL[row][cw] = l;
            } else if (MODE == 2) {
                FO[row][col] = v;
            } else {
                gs[mf][r] += v * w2c;
            }
        }
    if (MODE == 4) {
        #pragma unroll
        for (int mf = 0; mf < 2; ++mf)
            #pragma unroll
            for (int r = 0; r < 4; ++r) {
                float s = gs[mf][r];
                s += __shfl_xor(s, 1); s += __shfl_xor(s, 2);
                s += __shfl_xor(s, 4); s += __shfl_xor(s, 8);
                if (fr == 0) atomicAdd(&out32[mf * 16 + q * 4 + r], s);
            }
    }
}

// ---- chunk layer-2: Hrow = relu(IN @ W + b) + x[k]; XCN[e] += Hrow ----
__device__ __forceinline__ void layer_h2(
    const short (*INH)[C_DIM], const short (*INL)[C_DIM],
    const short* __restrict__ WH, const short* __restrict__ WL,
    const float* __restrict__ bias, const int* __restrict__ inst, int nrows,
    const float* __restrict__ xsrc, float (*XCN)[C_DIM])
{
    const int t = threadIdx.x, lane = t & 63, wq = t >> 6;
    const int fr = lane & 15, q = lane >> 4;
    f32x4 acc[2];
    #pragma unroll
    for (int i = 0; i < 2; ++i)
        #pragma unroll
        for (int r = 0; r < 4; ++r) acc[i][r] = 0.f;

    #pragma unroll 2
    for (int kf = 0; kf < 8; ++kf) {
        bf16x8 aH[2], aL[2];
        #pragma unroll
        for (int mf = 0; mf < 2; ++mf) {
            const int row = mf * 16 + fr;
            const int cc = (((kf << 2) + q) ^ (row & 7)) << 3;
            aH[mf] = *(const bf16x8*)&INH[row][cc];
            aL[mf] = *(const bf16x8*)&INL[row][cc];
        }
        const int wo = (((kf << 4) + wq) * 64 + lane) * 8;
        bf16x8 bH = *(const bf16x8*)&WH[wo];
        bf16x8 bL = *(const bf16x8*)&WL[wo];
        #pragma unroll
        for (int mf = 0; mf < 2; ++mf) {
            acc[mf] = __builtin_amdgcn_mfma_f32_16x16x32_bf16(aH[mf], bH, acc[mf], 0, 0, 0);
            acc[mf] = __builtin_amdgcn_mfma_f32_16x16x32_bf16(aH[mf], bL, acc[mf], 0, 0, 0);
            acc[mf] = __builtin_amdgcn_mfma_f32_16x16x32_bf16(aL[mf], bH, acc[mf], 0, 0, 0);
        }
    }
    const int col = (wq << 4) + fr;
    const float bb = bias[col];
    #pragma unroll
    for (int mf = 0; mf < 2; ++mf)
        #pragma unroll
        for (int r = 0; r < 4; ++r) {
            const int row = mf * 16 + q * 4 + r;
            if (row < nrows) {
                const int pk = inst[row];
                const int e  = pk >> 16;
                const int k  = pk & 0xffff;
                float v = fmaxf(acc[mf][r] + bb, 0.f) + xsrc[(size_t)k * C_DIM + col];
                atomicAdd(&XCN[e][col], v);
            }
        }
}

// ---------------- edge mega-kernel: 1024 threads ----------------
__global__ __launch_bounds__(1024, 1) void k_edge_mega(
    const unsigned long long* __restrict__ bits, const float* __restrict__ x,
    const int* __restrict__ tar,
    const short* __restrict__ WFH, const short* __restrict__ WFL,
    const float* __restrict__ b1x, const float* __restrict__ b2x,
    const float* __restrict__ bxij, const float* __restrict__ bcn1,
    const float* __restrict__ bcn2, const float* __restrict__ blin1,
    const float* __restrict__ betap, const float* __restrict__ w2,
    const float* __restrict__ b2o, float* __restrict__ out)
{
    __shared__ short AH[32][C_DIM], AL[32][C_DIM];   // plane A (32 KB)
    __shared__ short BH[32][C_DIM], BL[32][C_DIM];   // plane B (32 KB)
    __shared__ float CF[32][C_DIM];                  // f32: XCN accum -> FO (32 KB)
    __shared__ int   eij2[32][2];
    __shared__ int   inst[1024];
    __shared__ int   cntot;
    __shared__ float out32[32];
    const int e0 = blockIdx.x << 5;
    const int t = threadIdx.x;
    if (t < 32) {
        eij2[t][0] = tar[e0 + t];
        eij2[t][1] = tar[E_EDGES + e0 + t];
        out32[t] = 0.f;
    }
    if (t == 0) cntot = 0;
    __syncthreads();
    // zero XCN accumulator
    #pragma unroll
    for (int p = 0; p < 8; ++p) {
        int idx = (p << 10) + t;
        CF[idx >> 8][idx & 255] = 0.f;
    }
    // CN bit-scan: 32 threads/edge, 4 u64 words each
    {
        const int le = t >> 5, sub = t & 31;
        const size_t bi = (size_t)eij2[le][0] * 128;
        const size_t bj = (size_t)eij2[le][1] * 128;
        #pragma unroll
        for (int w4 = 0; w4 < 4; ++w4) {
            const int w = (sub << 2) + w4;
            unsigned long long m = bits[bi + w] & bits[bj + w];
            while (m) {
                int b = __builtin_ctzll(m);
                int slot = atomicAdd(&cntot, 1);
                if (slot < 1024) inst[slot] = (le << 16) | ((w << 6) + b);
                m &= m - 1;
            }
        }
    }
    __syncthreads();
    const int ctot = min(cntot, 1024);
    // ---- on-demand H: chunks of 32 CN instances ----
    for (int c0 = 0; c0 < ctot; c0 += 32) {
        const int nrows = min(32, ctot - c0);
        #pragma unroll
        for (int p = 0; p < 8; ++p) {
            int idx = (p << 10) + t;
            int r = idx >> 8, c = idx & 255;
            float v = 0.f;
            if (r < nrows) {
                int k = inst[c0 + r] & 0xffff;
                v = x[(size_t)k * C_DIM + c];
            }
            short h, l;
            split2(v, h, l);
            int cw = (((c >> 3) ^ (r & 7)) << 3) + (c & 7);
            AH[r][cw] = h;
            AL[r][cw] = l;
        }
        __syncthreads();
        layer_sb<0>(AH, AL, WFH + 0 * 65536, WFL + 0 * 65536, b1x,
                    BH, BL, nullptr, 0.f, nullptr, nullptr);
        __syncthreads();
        layer_h2(BH, BL, WFH + 1 * 65536, WFL + 1 * 65536, b2x,
                 inst + c0, nrows, x, CF);
        __syncthreads();
    }
    // ---- split XCN -> B planes ----
    #pragma unroll
    for (int p = 0; p < 8; ++p) {
        int idx = (p << 10) + t;
        int r = idx >> 8, c = idx & 255;
        short h, l;
        split2(CF[r][c], h, l);
        int cw = (((c >> 3) ^ (r & 7)) << 3) + (c & 7);
        BH[r][cw] = h;
        BL[r][cw] = l;
    }
    __syncthreads();   // CF fully read before XIJ overwrites it
    // ---- stage xij -> A planes ----
    #pragma unroll
    for (int p = 0; p < 8; ++p) {
        int idx = (p << 10) + t;
        int e = idx >> 8, c = idx & 255;
        float v = x[(size_t)eij2[e][0] * C_DIM + c] * x[(size_t)eij2[e][1] * C_DIM + c];
        short h, l;
        split2(v, h, l);
        int cw = (((c >> 3) ^ (e & 7)) << 3) + (c & 7);
        AH[e][cw] = h;
        AL[e][cw] = l;
    }
    __syncthreads();
    const float beta = betap[0];
    // XIJ = relu(xij @ xij_w + b) -> CF
    layer_sb<2>(AH, AL, WFH + 2 * 65536, WFL + 2 * 65536, bxij,
                nullptr, nullptr, CF, 0.f, nullptr, nullptr);
    __syncthreads();
    // T2 = relu(xcn @ xcn_w1 + b) -> A
    layer_sb<0>(BH, BL, WFH + 3 * 65536, WFL + 3 * 65536, bcn1,
                AH, AL, nullptr, 0.f, nullptr, nullptr);
    __syncthreads();
    // z = relu(T2 @ xcn_w2 + b)*beta + XIJ -> B
    layer_sb<1>(AH, AL, WFH + 4 * 65536, WFL + 4 * 65536, bcn2,
                BH, BL, CF, beta, nullptr, nullptr);
    __syncthreads();
    // out = relu(z @ lin_w1 + b) @ w2  (gemv fused)
    layer_sb<4>(BH, BL, WFH + 5 * 65536, WFL + 5 * 65536, blin1,
                nullptr, nullptr, nullptr, 0.f, w2, out32);
    __syncthreads();
    if (t < 32) out[e0 + t] = out32[t] + b2o[0];
}

extern "C" void kernel_launch(void* const* d_in, const int* in_sizes, int n_in,
                              void* d_out, int out_size, void* d_ws, size_t ws_size,
                              hipStream_t stream) {
    const float* x       = (const float*)d_in[0];
    const float* adj     = (const float*)d_in[1];
    const int*   tar_ei  = (const int*)  d_in[2];
    const float* xlin_w1 = (const float*)d_in[3];
    const float* xlin_b1 = (const float*)d_in[4];
    const float* xlin_w2 = (const float*)d_in[5];
    const float* xlin_b2 = (const float*)d_in[6];
    const float* xcn_w1  = (const float*)d_in[7];
    const float* xcn_b1  = (const float*)d_in[8];
    const float* xcn_w2  = (const float*)d_in[9];
    const float* xcn_b2  = (const float*)d_in[10];
    const float* xij_w   = (const float*)d_in[11];
    const float* xij_b   = (const float*)d_in[12];
    const float* lin_w1  = (const float*)d_in[13];
    const float* lin_b1  = (const float*)d_in[14];
    const float* lin_w2  = (const float*)d_in[15];
    const float* lin_b2  = (const float*)d_in[16];
    const float* beta    = (const float*)d_in[17];
    float* out = (float*)d_out;

    char* ws = (char*)d_ws;
    const size_t MB = 1024 * 1024;
    unsigned long long* bits = (unsigned long long*)(ws);       // 8 MB
    short* WFH  = (short*)(ws +  8 * MB);   // 768 KB
    short* WFL  = (short*)(ws +  9 * MB);   // 768 KB

    WPtrs wp;
    wp.p[0] = xlin_w1; wp.p[1] = xlin_w2; wp.p[2] = xij_w;
    wp.p[3] = xcn_w1;  wp.p[4] = xcn_w2;  wp.p[5] = lin_w1;

    hipLaunchKernelGGL(k_prep, dim3(48 + 2048), dim3(256), 0, stream,
                       adj, bits, wp, WFH, WFL);
    hipLaunchKernelGGL(k_edge_mega, dim3(E_EDGES / 32), dim3(1024), 0, stream,
                       bits, x, tar_ei, WFH, WFL,
                       xlin_b1, xlin_b2, xij_b, xcn_b1, xcn_b2, lin_b1,
                       beta, lin_w2, lin_b2, out);
}